// Round 1
// baseline (192.087 us; speedup 1.0000x reference)
//
#include <hip/hip_runtime.h>
#include <stdint.h>

typedef __attribute__((ext_vector_type(8))) short bf16x8;
typedef __attribute__((ext_vector_type(4))) float f32x4;
typedef __attribute__((ext_vector_type(4))) unsigned short u16x4;
typedef unsigned short u16;

#define NBATCH 4
#define SEQ    4096
#define CIN    512
#define HD     64
#define OC     576      // f32 elements per out row
#define NROW   (NBATCH * SEQ)

__device__ __forceinline__ float b2f(u16 u) {
    union { uint32_t i; float f; } w; w.i = ((uint32_t)u) << 16; return w.f;
}
__device__ __forceinline__ u16 f2b(float f) {
    union { float f; uint32_t i; } w; w.f = f;
    uint32_t r = w.i + 0x7fffu + ((w.i >> 16) & 1u);
    return (u16)(r >> 16);
}

// ---------------------------------------------------------------------------
// Kernel 1: transpose f32 weights into bf16 wt[192][512] (unchanged).
// ---------------------------------------------------------------------------
__global__ void prep_wt(const float* __restrict__ Wq, const float* __restrict__ Wk,
                        const float* __restrict__ Wv, u16* __restrict__ wt) {
    int row = blockIdx.x;            // 0..191
    int g = row >> 6, j = row & 63;
    const float* W = (g == 0) ? Wq : (g == 1) ? Wk : Wv;
    for (int k = threadIdx.x; k < CIN; k += blockDim.x)
        wt[row * CIN + k] = f2b(W[k * HD + j]);
}

// ---------------------------------------------------------------------------
// Kernel 2: QKV projection via MFMA + fused f32 x-copy (unchanged).
// ---------------------------------------------------------------------------
__global__ __launch_bounds__(256) void proj(
    const float* __restrict__ x, const u16* __restrict__ wt,
    const float* __restrict__ bq, const float* __restrict__ bk, const float* __restrict__ bv,
    u16* __restrict__ qb, u16* __restrict__ kbuf, u16* __restrict__ vtb,
    float* __restrict__ out)
{
    int lane = threadIdx.x & 63, wid = threadIdx.x >> 6;
    int m = lane & 15, quad = lane >> 4;
    int wg = blockIdx.x * 4 + wid;   // 0..1023
    int r0 = wg * 16;                // global row (n*SEQ + t)

    f32x4 acc[12];
#pragma unroll
    for (int i = 0; i < 12; i++) acc[i] = (f32x4){0.f, 0.f, 0.f, 0.f};

    const float* xp = x + (size_t)(r0 + m) * CIN + quad * 8;
    float* op = out + (size_t)(r0 + m) * OC + quad * 8;

    for (int c = 0; c < 16; c++) {
        f32x4 lo = *(const f32x4*)(xp + c * 32);
        f32x4 hi = *(const f32x4*)(xp + c * 32 + 4);
        *(f32x4*)(op + c * 32)     = lo;       // exact f32 x-copy
        *(f32x4*)(op + c * 32 + 4) = hi;
        bf16x8 a;
#pragma unroll
        for (int j = 0; j < 4; j++) { a[j] = (short)f2b(lo[j]); a[4 + j] = (short)f2b(hi[j]); }
#pragma unroll
        for (int nt = 0; nt < 12; nt++) {
            bf16x8 b = *(const bf16x8*)(wt + (size_t)(nt * 16 + m) * CIN + c * 32 + quad * 8);
            acc[nt] = __builtin_amdgcn_mfma_f32_16x16x32_bf16(a, b, acc[nt], 0, 0, 0);
        }
    }

    int n  = r0 >> 12;          // batch
    int tl = r0 & (SEQ - 1);    // t within batch

#pragma unroll
    for (int nt = 0; nt < 4; nt++) {
        int bi = nt * 16 + m;
        float biasq = bq[bi], biask = bk[bi];
#pragma unroll
        for (int reg = 0; reg < 4; reg++) {
            size_t r = (size_t)(r0 + quad * 4 + reg);
            qb[r * HD + bi]   = f2b(acc[nt][reg] + biasq);
            kbuf[r * HD + bi] = f2b(acc[4 + nt][reg] + biask);
        }
    }
#pragma unroll
    for (int nt = 0; nt < 4; nt++) {
        int bi = nt * 16 + m;
        float biasv = bv[bi];
        u16x4 pk;
#pragma unroll
        for (int reg = 0; reg < 4; reg++) pk[reg] = f2b(acc[8 + nt][reg] + biasv);
        u16* vp = vtb + (size_t)(n * HD + bi) * SEQ + tl + quad * 4;
        *(u16x4*)vp = pk;
    }
}

// ---------------------------------------------------------------------------
// Kernel 3: causal flash attention, TRANSPOSED-S formulation.
// R1 restructure: one 16-query tile per block, 8 waves (512 thr), 8-way key
// split, LDS merge of 8 partials. Grid 1024 with LPT ordering (heaviest
// tiles dispatched first). LDS = 54.3 KB -> 3 blocks/CU -> up to 24
// waves/CU (vs 8 before): attacks the latency-bound profile
// (MfmaUtil 5%, VALUBusy 23%, occupancy 19%).
//
// S^T = K.Q^T via mfma(A=K-frag, B=Q-frag): D col = query = lane&15,
// row = key_local = quad*4+reg. Softmax state (m,l) is ONE scalar per lane
// (its query t0+m): max/sum = in-register tree over 16 regs + shfl 16,32.
// O^T = V^T.P^T: A = vt frag (contiguous), B = P^T from per-wave LDS.
// Partials merged via LDS (flash combine), contiguous f32x4 stores.
// ---------------------------------------------------------------------------
__global__ __launch_bounds__(512) void attn(
    const u16* __restrict__ qb, const u16* __restrict__ kbuf,
    const u16* __restrict__ vtb, float* __restrict__ out)
{
    __shared__ __align__(16) short plds[8][16 * 72];   // P^T per wave (18 KiB)
    __shared__ __align__(16) float ldso[8][16][68];    // O^T partials (34 KiB)
    __shared__ float ldsm[8][16];                      // m partials [w][t]
    __shared__ float ldsl[8][16];                      // l partials [w][t]

    int tid = threadIdx.x;
    int lane = tid & 63, w = tid >> 6;   // 8 waves
    int m = lane & 15, quad = lane >> 4;
    int idx = blockIdx.x;
    int batch = idx & 3;
    int j = 255 - (idx >> 2);            // LPT: heaviest tiles (largest j) first
    int t0 = j * 16;
    int nkb = (j >> 2) + 1;              // 64-key blocks covering keys < t0+16

    const u16* kp  = kbuf + (size_t)(batch * SEQ + m) * HD + quad * 8;  // + s*HD
    const u16* vp  = vtb + (size_t)(batch * HD + m) * SEQ + quad * 8;   // + vblk*16*SEQ + s
    const u16* qpb = qb + (size_t)(batch * SEQ + m) * HD + quad * 8;    // + t0*HD

    const float SC = 0.125f * 1.44269504088896f;  // scale * log2(e)
    short* pw = plds[w];

    // Q B-frag (query = lane&15 = m)
    bf16x8 bq0 = *(const bf16x8*)(qpb + (size_t)t0 * HD);
    bf16x8 bq1 = *(const bf16x8*)(qpb + (size_t)t0 * HD + 32);

    float mst = -1e30f, lst = 0.f;
    f32x4 o[4];
#pragma unroll
    for (int nt = 0; nt < 4; nt++) o[nt] = (f32x4){0.f, 0.f, 0.f, 0.f};

    int cnt = (nkb > w) ? ((nkb - w + 7) >> 3) : 0;
    int kb = w;

    // preload K A-frags for first kb (memory-safe even if cnt==0: kb<=7)
    bf16x8 k0[4], k1[4];
#pragma unroll
    for (int st = 0; st < 4; st++) {
        k0[st] = *(const bf16x8*)(kp + (size_t)(kb * 64 + st * 16) * HD);
        k1[st] = *(const bf16x8*)(kp + (size_t)(kb * 64 + st * 16) * HD + 32);
    }

    for (int it = 0; it < cnt; it++, kb += 8) {
        int s0 = kb * 64;

        // S^T = K Q^T (col = query, row = key_local)
        f32x4 s[4];
#pragma unroll
        for (int st = 0; st < 4; st++) {
            f32x4 a = (f32x4){0.f, 0.f, 0.f, 0.f};
            a = __builtin_amdgcn_mfma_f32_16x16x32_bf16(k0[st], bq0, a, 0, 0, 0);
            a = __builtin_amdgcn_mfma_f32_16x16x32_bf16(k1[st], bq1, a, 0, 0, 0);
            s[st] = a;
        }

        // V loads (current block) + K prefetch (next) hide behind softmax
        bf16x8 vf0[4], vf1[4];
#pragma unroll
        for (int nt = 0; nt < 4; nt++) {
            vf0[nt] = *(const bf16x8*)(vp + (size_t)(nt * 16) * SEQ + s0);
            vf1[nt] = *(const bf16x8*)(vp + (size_t)(nt * 16) * SEQ + s0 + 32);
        }
        if (it + 1 < cnt) {
            int sn = s0 + 512;           // next key-block for this wave (step 8)
#pragma unroll
            for (int st = 0; st < 4; st++) {
                k0[st] = *(const bf16x8*)(kp + (size_t)(sn + st * 16) * HD);
                k1[st] = *(const bf16x8*)(kp + (size_t)(sn + st * 16) * HD + 32);
            }
        }

        // scale; causal mask only on the diagonal block (kb == nkb-1)
        if (kb == nkb - 1) {
#pragma unroll
            for (int st = 0; st < 4; st++)
#pragma unroll
                for (int r = 0; r < 4; r++) {
                    int key = s0 + st * 16 + quad * 4 + r;
                    s[st][r] = (key <= t0 + m) ? s[st][r] * SC : -1e30f;
                }
        } else {
#pragma unroll
            for (int st = 0; st < 4; st++)
#pragma unroll
                for (int r = 0; r < 4; r++) s[st][r] *= SC;
        }

        // per-query max: in-register tree (16) + cross-quad shfl (2 rounds)
        float mx = -1e30f;
#pragma unroll
        for (int st = 0; st < 4; st++) {
            float a01 = fmaxf(s[st][0], s[st][1]);
            float a23 = fmaxf(s[st][2], s[st][3]);
            mx = fmaxf(mx, fmaxf(a01, a23));
        }
        mx = fmaxf(mx, __shfl_xor(mx, 16, 64));
        mx = fmaxf(mx, __shfl_xor(mx, 32, 64));

        float mn = fmaxf(mst, mx);
        float alpha = exp2f(mst - mn);
        mst = mn;

        // P = 2^(s - m); per-query sum same pattern
        float ls = 0.f;
#pragma unroll
        for (int st = 0; st < 4; st++) {
#pragma unroll
            for (int r = 0; r < 4; r++) s[st][r] = exp2f(s[st][r] - mn);
            ls += (s[st][0] + s[st][1]) + (s[st][2] + s[st][3]);
        }
        ls += __shfl_xor(ls, 16, 64);
        ls += __shfl_xor(ls, 32, 64);
        lst = lst * alpha + ls;
#pragma unroll
        for (int nt = 0; nt < 4; nt++)
#pragma unroll
            for (int r = 0; r < 4; r++) o[nt][r] *= alpha;

        // P^T -> LDS (packed u16x4 per st: consecutive key_local regs)
#pragma unroll
        for (int st = 0; st < 4; st++) {
            u16x4 pk;
#pragma unroll
            for (int r = 0; r < 4; r++) pk[r] = f2b(s[st][r]);
            *(u16x4*)(pw + m * 72 + st * 16 + quad * 4) = pk;
        }
        __asm__ volatile("" ::: "memory");

        // B-frag read: B[n=query=m][k=key=quad*8+j]
        bf16x8 p0 = *(const bf16x8*)(pw + m * 72 + quad * 8);
        bf16x8 p1 = *(const bf16x8*)(pw + m * 72 + 32 + quad * 8);

        // O^T += V^T P^T
#pragma unroll
        for (int nt = 0; nt < 4; nt++) {
            o[nt] = __builtin_amdgcn_mfma_f32_16x16x32_bf16(vf0[nt], p0, o[nt], 0, 0, 0);
            o[nt] = __builtin_amdgcn_mfma_f32_16x16x32_bf16(vf1[nt], p1, o[nt], 0, 0, 0);
        }
    }

    // publish partials: O^T lane holds (t = m, v = nt*16 + quad*4 + r).
    // Waves with cnt==0 publish (m=-1e30, l=0, O=0) -> zero weight in merge.
    if (quad == 0) { ldsm[w][m] = mst; ldsl[w][m] = lst; }
#pragma unroll
    for (int nt = 0; nt < 4; nt++)
        *(f32x4*)&ldso[w][m][nt * 16 + quad * 4] = o[nt];
    __syncthreads();

    // merge 8 partials: thread tau (<256) -> (t = tau>>4, v = (tau&15)*4 .. +3)
    if (tid < 256) {
        int t = tid >> 4, vg = tid & 15;
        float mmax = -1e30f;
#pragma unroll
        for (int u = 0; u < 8; u++) mmax = fmaxf(mmax, ldsm[u][t]);
        float L = 0.f;
        f32x4 acc = (f32x4){0.f, 0.f, 0.f, 0.f};
#pragma unroll
        for (int u = 0; u < 8; u++) {
            float c = exp2f(ldsm[u][t] - mmax);
            L += ldsl[u][t] * c;
            f32x4 ov = *(const f32x4*)&ldso[u][t][vg * 4];
#pragma unroll
            for (int i2 = 0; i2 < 4; i2++) acc[i2] += ov[i2] * c;
        }
        float inv = 1.0f / L;
        f32x4 res;
#pragma unroll
        for (int i2 = 0; i2 < 4; i2++) res[i2] = acc[i2] * inv;
        *(f32x4*)(out + (size_t)(batch * SEQ + t0 + t) * OC + CIN + vg * 4) = res;
    }
}

// ---------------------------------------------------------------------------
extern "C" void kernel_launch(void* const* d_in, const int* in_sizes, int n_in,
                              void* d_out, int out_size, void* d_ws, size_t ws_size,
                              hipStream_t stream) {
    const float* x  = (const float*)d_in[0];
    const float* Wq = (const float*)d_in[1];
    const float* bq = (const float*)d_in[2];
    const float* Wk = (const float*)d_in[3];
    const float* bk = (const float*)d_in[4];
    const float* Wv = (const float*)d_in[5];
    const float* bv = (const float*)d_in[6];
    float* out = (float*)d_out;

    u16* ws  = (u16*)d_ws;
    u16* wt  = ws;                          // 192*512 elems (pad to 128K)
    u16* qb  = ws + 131072;                 // 16384*64 = 1M elems
    u16* kb  = qb + 16384 * 64;
    u16* vtb = kb + 16384 * 64;             // transposed v: [4][64][4096]

    prep_wt<<<dim3(192), dim3(256), 0, stream>>>(Wq, Wk, Wv, wt);
    proj<<<dim3(256), dim3(256), 0, stream>>>(x, wt, bq, bk, bv, qb, kb, vtb, out);
    attn<<<dim3(1024), dim3(512), 0, stream>>>(qb, kb, vtb, out);
}

// Round 2
// 172.242 us; speedup vs baseline: 1.1152x; 1.1152x over previous
//
#include <hip/hip_runtime.h>
#include <stdint.h>

typedef __attribute__((ext_vector_type(8))) short bf16x8;
typedef __attribute__((ext_vector_type(4))) float f32x4;
typedef __attribute__((ext_vector_type(4))) unsigned short u16x4;
typedef unsigned short u16;

#define NBATCH 4
#define SEQ    4096
#define CIN    512
#define HD     64
#define OC     576      // f32 elements per out row
#define NROW   (NBATCH * SEQ)

__device__ __forceinline__ float b2f(u16 u) {
    union { uint32_t i; float f; } w; w.i = ((uint32_t)u) << 16; return w.f;
}
__device__ __forceinline__ u16 f2b(float f) {
    union { float f; uint32_t i; } w; w.f = f;
    uint32_t r = w.i + 0x7fffu + ((w.i >> 16) & 1u);
    return (u16)(r >> 16);
}

// ---------------------------------------------------------------------------
// Kernel 1: transpose f32 weights into bf16 wt[192][512] (unchanged).
// ---------------------------------------------------------------------------
__global__ void prep_wt(const float* __restrict__ Wq, const float* __restrict__ Wk,
                        const float* __restrict__ Wv, u16* __restrict__ wt) {
    int row = blockIdx.x;            // 0..191
    int g = row >> 6, j = row & 63;
    const float* W = (g == 0) ? Wq : (g == 1) ? Wk : Wv;
    for (int k = threadIdx.x; k < CIN; k += blockDim.x)
        wt[row * CIN + k] = f2b(W[k * HD + j]);
}

// ---------------------------------------------------------------------------
// Kernel 2: QKV projection via MFMA + fused f32 x-copy (unchanged).
// ---------------------------------------------------------------------------
__global__ __launch_bounds__(256) void proj(
    const float* __restrict__ x, const u16* __restrict__ wt,
    const float* __restrict__ bq, const float* __restrict__ bk, const float* __restrict__ bv,
    u16* __restrict__ qb, u16* __restrict__ kbuf, u16* __restrict__ vtb,
    float* __restrict__ out)
{
    int lane = threadIdx.x & 63, wid = threadIdx.x >> 6;
    int m = lane & 15, quad = lane >> 4;
    int wg = blockIdx.x * 4 + wid;   // 0..1023
    int r0 = wg * 16;                // global row (n*SEQ + t)

    f32x4 acc[12];
#pragma unroll
    for (int i = 0; i < 12; i++) acc[i] = (f32x4){0.f, 0.f, 0.f, 0.f};

    const float* xp = x + (size_t)(r0 + m) * CIN + quad * 8;
    float* op = out + (size_t)(r0 + m) * OC + quad * 8;

    for (int c = 0; c < 16; c++) {
        f32x4 lo = *(const f32x4*)(xp + c * 32);
        f32x4 hi = *(const f32x4*)(xp + c * 32 + 4);
        *(f32x4*)(op + c * 32)     = lo;       // exact f32 x-copy
        *(f32x4*)(op + c * 32 + 4) = hi;
        bf16x8 a;
#pragma unroll
        for (int j = 0; j < 4; j++) { a[j] = (short)f2b(lo[j]); a[4 + j] = (short)f2b(hi[j]); }
#pragma unroll
        for (int nt = 0; nt < 12; nt++) {
            bf16x8 b = *(const bf16x8*)(wt + (size_t)(nt * 16 + m) * CIN + c * 32 + quad * 8);
            acc[nt] = __builtin_amdgcn_mfma_f32_16x16x32_bf16(a, b, acc[nt], 0, 0, 0);
        }
    }

    int n  = r0 >> 12;          // batch
    int tl = r0 & (SEQ - 1);    // t within batch

#pragma unroll
    for (int nt = 0; nt < 4; nt++) {
        int bi = nt * 16 + m;
        float biasq = bq[bi], biask = bk[bi];
#pragma unroll
        for (int reg = 0; reg < 4; reg++) {
            size_t r = (size_t)(r0 + quad * 4 + reg);
            qb[r * HD + bi]   = f2b(acc[nt][reg] + biasq);
            kbuf[r * HD + bi] = f2b(acc[4 + nt][reg] + biask);
        }
    }
#pragma unroll
    for (int nt = 0; nt < 4; nt++) {
        int bi = nt * 16 + m;
        float biasv = bv[bi];
        u16x4 pk;
#pragma unroll
        for (int reg = 0; reg < 4; reg++) pk[reg] = f2b(acc[8 + nt][reg] + biasv);
        u16* vp = vtb + (size_t)(n * HD + bi) * SEQ + tl + quad * 4;
        *(u16x4*)vp = pk;
    }
}

// ---------------------------------------------------------------------------
// Kernel 3: causal flash attention, transposed-S, R2 restructure for
// ARITHMETIC INTENSITY. Diagnosis from R0/R1: both rounds sustain the same
// ~8 TB/s of L2/L3 traffic (532 MB/dispatch) with all pipes <25% busy ->
// shared-cache-BW-bound. Fix: QBLK=64 queries per block (4 sub-tiles of 16
// per wave), so each K/V fragment loaded from cache is reused 4x ->
// traffic /4 (~135 MB). Plus XCD-batch affinity (2 XCDs per batch) so each
// XCD's L2 holds only its batch's K+V (2 MB < 4 MB) -> L2-resident.
//
// 8 waves, 8-way key split. All key-blocks except the last (kb == b4) are
// causally FULL for every sub-tile; the last gets the per-element diagonal
// mask. Partial merge across waves runs in 4 rounds (one per sub-tile)
// reusing the same 34 KB LDS buffer.
// ---------------------------------------------------------------------------
__global__ __launch_bounds__(512, 2) void attn(
    const u16* __restrict__ qb, const u16* __restrict__ kbuf,
    const u16* __restrict__ vtb, float* __restrict__ out)
{
    __shared__ __align__(16) short plds[8][16 * 72];   // P^T per wave (18 KiB)
    __shared__ __align__(16) float ldso[8][16][68];    // O^T partials (34 KiB)
    __shared__ float ldsm[8][16];                      // m partials [w][t]
    __shared__ float ldsl[8][16];                      // l partials [w][t]

    int tid = threadIdx.x;
    int lane = tid & 63, w = tid >> 6;   // 8 waves
    int m = lane & 15, quad = lane >> 4;

    // 256 blocks: xcd = idx&7 (HW round-robins consecutive blockIdx across
    // XCDs); 2 XCDs per batch -> per-XCD working set = 1 batch K+V = 2 MB.
    // Within each XCD: LPT, heaviest query-block first.
    int idx = blockIdx.x;
    int xcd = idx & 7, slot = idx >> 3;          // slot 0..31
    int batch = xcd >> 1;
    int b4 = 63 - (slot * 2 + (xcd & 1));        // 0..63, heavy first
    int qt0 = b4 * 64;                           // first query of this block
    int nkb = b4 + 1;                            // 64-key blocks needed

    const u16* kp  = kbuf + (size_t)(batch * SEQ + m) * HD + quad * 8;  // + s*HD
    const u16* vp  = vtb + (size_t)(batch * HD + m) * SEQ + quad * 8;   // + nt*16*SEQ + s
    const u16* qpb = qb + (size_t)(batch * SEQ + qt0 + m) * HD + quad * 8;

    const float SC = 0.125f * 1.44269504088896f;  // scale * log2(e)
    short* pw = plds[w];

    // Q B-frags for the 4 query sub-tiles (query = m within sub-tile)
    bf16x8 q0[4], q1[4];
#pragma unroll
    for (int q = 0; q < 4; q++) {
        q0[q] = *(const bf16x8*)(qpb + (size_t)(q * 16) * HD);
        q1[q] = *(const bf16x8*)(qpb + (size_t)(q * 16) * HD + 32);
    }

    float mst[4], lst[4];
    f32x4 o[4][4];                 // [q][nt] O^T accumulators (64 VGPR)
#pragma unroll
    for (int q = 0; q < 4; q++) {
        mst[q] = -1e30f; lst[q] = 0.f;
#pragma unroll
        for (int nt = 0; nt < 4; nt++) o[q][nt] = (f32x4){0.f, 0.f, 0.f, 0.f};
    }

    int cnt = (nkb > w) ? ((nkb - w + 7) >> 3) : 0;
    int kb = w;
    int lastkb = nkb - 1;

    // preload K A-frags for first kb (memory-safe even if cnt==0: kb<=7)
    bf16x8 k0[4], k1[4];
#pragma unroll
    for (int st = 0; st < 4; st++) {
        k0[st] = *(const bf16x8*)(kp + (size_t)(kb * 64 + st * 16) * HD);
        k1[st] = *(const bf16x8*)(kp + (size_t)(kb * 64 + st * 16) * HD + 32);
    }

    for (int it = 0; it < cnt; it++, kb += 8) {
        int s0 = kb * 64;
        bool diag = (kb == lastkb);

        // V loads for this key-block: reused by all 4 sub-tiles
        bf16x8 vf0[4], vf1[4];
#pragma unroll
        for (int nt = 0; nt < 4; nt++) {
            vf0[nt] = *(const bf16x8*)(vp + (size_t)(nt * 16) * SEQ + s0);
            vf1[nt] = *(const bf16x8*)(vp + (size_t)(nt * 16) * SEQ + s0 + 32);
        }

#pragma unroll
        for (int q = 0; q < 4; q++) {
            // S^T = K Q^T (col = query m, row = key_local quad*4+r)
            f32x4 s[4];
#pragma unroll
            for (int st = 0; st < 4; st++) {
                f32x4 a = (f32x4){0.f, 0.f, 0.f, 0.f};
                a = __builtin_amdgcn_mfma_f32_16x16x32_bf16(k0[st], q0[q], a, 0, 0, 0);
                a = __builtin_amdgcn_mfma_f32_16x16x32_bf16(k1[st], q1[q], a, 0, 0, 0);
                s[st] = a;
            }

            // after the last use of k0/k1 this iteration: prefetch next kb
            if (q == 3 && it + 1 < cnt) {
                int sn = s0 + 512;
#pragma unroll
                for (int st = 0; st < 4; st++) {
                    k0[st] = *(const bf16x8*)(kp + (size_t)(sn + st * 16) * HD);
                    k1[st] = *(const bf16x8*)(kp + (size_t)(sn + st * 16) * HD + 32);
                }
            }

            // scale; diagonal mask only on the last key-block
            if (diag) {
#pragma unroll
                for (int st = 0; st < 4; st++)
#pragma unroll
                    for (int r = 0; r < 4; r++) {
                        int key = s0 + st * 16 + quad * 4 + r;
                        s[st][r] = (key <= qt0 + q * 16 + m) ? s[st][r] * SC : -1e30f;
                    }
            } else {
#pragma unroll
                for (int st = 0; st < 4; st++)
#pragma unroll
                    for (int r = 0; r < 4; r++) s[st][r] *= SC;
            }

            // per-query max: in-register tree (16) + cross-quad shfl (2)
            float mx = -1e30f;
#pragma unroll
            for (int st = 0; st < 4; st++) {
                float a01 = fmaxf(s[st][0], s[st][1]);
                float a23 = fmaxf(s[st][2], s[st][3]);
                mx = fmaxf(mx, fmaxf(a01, a23));
            }
            mx = fmaxf(mx, __shfl_xor(mx, 16, 64));
            mx = fmaxf(mx, __shfl_xor(mx, 32, 64));

            float mn = fmaxf(mst[q], mx);
            float alpha = exp2f(mst[q] - mn);
            mst[q] = mn;

            // P = 2^(s - m); per-query sum same pattern
            float ls = 0.f;
#pragma unroll
            for (int st = 0; st < 4; st++) {
#pragma unroll
                for (int r = 0; r < 4; r++) s[st][r] = exp2f(s[st][r] - mn);
                ls += (s[st][0] + s[st][1]) + (s[st][2] + s[st][3]);
            }
            ls += __shfl_xor(ls, 16, 64);
            ls += __shfl_xor(ls, 32, 64);
            lst[q] = lst[q] * alpha + ls;
#pragma unroll
            for (int nt = 0; nt < 4; nt++)
#pragma unroll
                for (int r = 0; r < 4; r++) o[q][nt][r] *= alpha;

            // P^T -> LDS (packed u16x4 per st)
#pragma unroll
            for (int st = 0; st < 4; st++) {
                u16x4 pk;
#pragma unroll
                for (int r = 0; r < 4; r++) pk[r] = f2b(s[st][r]);
                *(u16x4*)(pw + m * 72 + st * 16 + quad * 4) = pk;
            }
            __asm__ volatile("" ::: "memory");

            // B-frag read: B[n=query=m][k=key=quad*8+j]
            bf16x8 p0 = *(const bf16x8*)(pw + m * 72 + quad * 8);
            bf16x8 p1 = *(const bf16x8*)(pw + m * 72 + 32 + quad * 8);
            __asm__ volatile("" ::: "memory");

            // O^T += V^T P^T  (V frags reused across all 4 sub-tiles)
#pragma unroll
            for (int nt = 0; nt < 4; nt++) {
                o[q][nt] = __builtin_amdgcn_mfma_f32_16x16x32_bf16(vf0[nt], p0, o[q][nt], 0, 0, 0);
                o[q][nt] = __builtin_amdgcn_mfma_f32_16x16x32_bf16(vf1[nt], p1, o[q][nt], 0, 0, 0);
            }
        }
    }

    // merge: 4 rounds, one per query sub-tile, reusing the 34 KB ldso.
    // Waves with cnt==0 (or sub-tile untouched) publish (m=-1e30,l=0,O=0)
    // -> zero weight (wave 0 always has work, so mmax > -1e30).
#pragma unroll
    for (int q = 0; q < 4; q++) {
        if (quad == 0) { ldsm[w][m] = mst[q]; ldsl[w][m] = lst[q]; }
#pragma unroll
        for (int nt = 0; nt < 4; nt++)
            *(f32x4*)&ldso[w][m][nt * 16 + quad * 4] = o[q][nt];
        __syncthreads();

        if (tid < 256) {
            int t = tid >> 4, vg = tid & 15;
            float mmax = -1e30f;
#pragma unroll
            for (int u = 0; u < 8; u++) mmax = fmaxf(mmax, ldsm[u][t]);
            float L = 0.f;
            f32x4 acc = (f32x4){0.f, 0.f, 0.f, 0.f};
#pragma unroll
            for (int u = 0; u < 8; u++) {
                float c = exp2f(ldsm[u][t] - mmax);
                L += ldsl[u][t] * c;
                f32x4 ov = *(const f32x4*)&ldso[u][t][vg * 4];
#pragma unroll
                for (int i2 = 0; i2 < 4; i2++) acc[i2] += ov[i2] * c;
            }
            float inv = 1.0f / L;
            f32x4 res;
#pragma unroll
            for (int i2 = 0; i2 < 4; i2++) res[i2] = acc[i2] * inv;
            *(f32x4*)(out + (size_t)(batch * SEQ + qt0 + q * 16 + t) * OC + CIN + vg * 4) = res;
        }
        __syncthreads();
    }
}

// ---------------------------------------------------------------------------
extern "C" void kernel_launch(void* const* d_in, const int* in_sizes, int n_in,
                              void* d_out, int out_size, void* d_ws, size_t ws_size,
                              hipStream_t stream) {
    const float* x  = (const float*)d_in[0];
    const float* Wq = (const float*)d_in[1];
    const float* bq = (const float*)d_in[2];
    const float* Wk = (const float*)d_in[3];
    const float* bk = (const float*)d_in[4];
    const float* Wv = (const float*)d_in[5];
    const float* bv = (const float*)d_in[6];
    float* out = (float*)d_out;

    u16* ws  = (u16*)d_ws;
    u16* wt  = ws;                          // 192*512 elems (pad to 128K)
    u16* qb  = ws + 131072;                 // 16384*64 = 1M elems
    u16* kb  = qb + 16384 * 64;
    u16* vtb = kb + 16384 * 64;             // transposed v: [4][64][4096]

    prep_wt<<<dim3(192), dim3(256), 0, stream>>>(Wq, Wk, Wv, wt);
    proj<<<dim3(256), dim3(256), 0, stream>>>(x, wt, bq, bk, bv, qb, kb, vtb, out);
    attn<<<dim3(256), dim3(512), 0, stream>>>(qb, kb, vtb, out);
}

// Round 3
// 159.751 us; speedup vs baseline: 1.2024x; 1.0782x over previous
//
#include <hip/hip_runtime.h>
#include <stdint.h>

typedef __attribute__((ext_vector_type(8))) short bf16x8;
typedef __attribute__((ext_vector_type(4))) float f32x4;
typedef __attribute__((ext_vector_type(4))) unsigned short u16x4;
typedef unsigned short u16;

#define NBATCH 4
#define SEQ    4096
#define CIN    512
#define HD     64
#define OC     576      // f32 elements per out row
#define NROW   (NBATCH * SEQ)

__device__ __forceinline__ float b2f(u16 u) {
    union { uint32_t i; float f; } w; w.i = ((uint32_t)u) << 16; return w.f;
}
__device__ __forceinline__ u16 f2b(float f) {
    union { float f; uint32_t i; } w; w.f = f;
    uint32_t r = w.i + 0x7fffu + ((w.i >> 16) & 1u);
    return (u16)(r >> 16);
}
// pack two f32 -> two bf16 (RTNE) in one VGPR: lo = a, hi = b
__device__ __forceinline__ uint32_t cvtpk_bf16(float a, float b) {
    uint32_t r;
    asm("v_cvt_pk_bf16_f32 %0, %1, %2" : "=v"(r) : "v"(a), "v"(b));
    return r;
}

// ---------------------------------------------------------------------------
// Kernel 1: transpose f32 weights into bf16 wt[192][512] (unchanged).
// ---------------------------------------------------------------------------
__global__ void prep_wt(const float* __restrict__ Wq, const float* __restrict__ Wk,
                        const float* __restrict__ Wv, u16* __restrict__ wt) {
    int row = blockIdx.x;            // 0..191
    int g = row >> 6, j = row & 63;
    const float* W = (g == 0) ? Wq : (g == 1) ? Wk : Wv;
    for (int k = threadIdx.x; k < CIN; k += blockDim.x)
        wt[row * CIN + k] = f2b(W[k * HD + j]);
}

// ---------------------------------------------------------------------------
// Kernel 2: QKV projection via MFMA + fused f32 x-copy.
// R3 change: Q is PRE-SCALED by 0.125*log2(e) in f32 before bf16 rounding,
// so the attention kernel's scores come out of the QK MFMA ready for exp2
// (removes 16 VALU muls per q-chain per key-block in attn).
// ---------------------------------------------------------------------------
__global__ __launch_bounds__(256) void proj(
    const float* __restrict__ x, const u16* __restrict__ wt,
    const float* __restrict__ bq, const float* __restrict__ bk, const float* __restrict__ bv,
    u16* __restrict__ qb, u16* __restrict__ kbuf, u16* __restrict__ vtb,
    float* __restrict__ out)
{
    int lane = threadIdx.x & 63, wid = threadIdx.x >> 6;
    int m = lane & 15, quad = lane >> 4;
    int wg = blockIdx.x * 4 + wid;   // 0..1023
    int r0 = wg * 16;                // global row (n*SEQ + t)

    f32x4 acc[12];
#pragma unroll
    for (int i = 0; i < 12; i++) acc[i] = (f32x4){0.f, 0.f, 0.f, 0.f};

    const float* xp = x + (size_t)(r0 + m) * CIN + quad * 8;
    float* op = out + (size_t)(r0 + m) * OC + quad * 8;

    for (int c = 0; c < 16; c++) {
        f32x4 lo = *(const f32x4*)(xp + c * 32);
        f32x4 hi = *(const f32x4*)(xp + c * 32 + 4);
        *(f32x4*)(op + c * 32)     = lo;       // exact f32 x-copy
        *(f32x4*)(op + c * 32 + 4) = hi;
        bf16x8 a;
#pragma unroll
        for (int j = 0; j < 4; j++) { a[j] = (short)f2b(lo[j]); a[4 + j] = (short)f2b(hi[j]); }
#pragma unroll
        for (int nt = 0; nt < 12; nt++) {
            bf16x8 b = *(const bf16x8*)(wt + (size_t)(nt * 16 + m) * CIN + c * 32 + quad * 8);
            acc[nt] = __builtin_amdgcn_mfma_f32_16x16x32_bf16(a, b, acc[nt], 0, 0, 0);
        }
    }

    int n  = r0 >> 12;          // batch
    int tl = r0 & (SEQ - 1);    // t within batch

    const float SCQ = 0.125f * 1.44269504088896f;   // scale * log2(e), baked into Q

#pragma unroll
    for (int nt = 0; nt < 4; nt++) {
        int bi = nt * 16 + m;
        float biasq = bq[bi], biask = bk[bi];
#pragma unroll
        for (int reg = 0; reg < 4; reg++) {
            size_t r = (size_t)(r0 + quad * 4 + reg);
            qb[r * HD + bi]   = f2b((acc[nt][reg] + biasq) * SCQ);
            kbuf[r * HD + bi] = f2b(acc[4 + nt][reg] + biask);
        }
    }
#pragma unroll
    for (int nt = 0; nt < 4; nt++) {
        int bi = nt * 16 + m;
        float biasv = bv[bi];
        u16x4 pk;
#pragma unroll
        for (int reg = 0; reg < 4; reg++) pk[reg] = f2b(acc[8 + nt][reg] + biasv);
        u16* vp = vtb + (size_t)(n * HD + bi) * SEQ + tl + quad * 4;
        *(u16x4*)vp = pk;
    }
}

// ---------------------------------------------------------------------------
// Kernel 3: causal flash attention. R3 restructure for UNIFORM LOAD +
// SHORT SOFTMAX CHAIN. Diagnosis from R2: grid 256 = 1 block/CU means the
// CU holding the heaviest query-block (64 key-visits) is the critical path
// while light CUs idle (occupancy decays to ~12%); softmax VALU chain
// dominates MFMA 3:1 (VALUBusy 29% vs MfmaUtil 6.4%).
//
// Fixes:
//  - QBLK=32, ANTITHETIC PAIRING: block p processes tiles (127-p) then p
//    -> every block does ~65 key-block visits (exactly uniform). XCD-batch
//    affinity kept (2 XCDs per batch; K+V+Q = 1.5 MB, L2-resident).
//  - Q pre-scaled in proj -> no per-element scale mul; non-diag blocks do
//    no VALU on s before max.
//  - l computed by ones-row MFMA on P^T (2 MFMA) instead of 16 adds+2 shfl.
//  - defer-max (THR=8): skip alpha-rescale when max grew <= 8.
//  - v_cvt_pk_bf16_f32 packing (8 ops vs 48).
//  - per-(wave,q) LDS P regions: the 2 q-chains are no longer serialized
//    by the shared buffer; single compiler barrier between pack and read.
// ---------------------------------------------------------------------------
__global__ __launch_bounds__(512, 2) void attn(
    const u16* __restrict__ qb, const u16* __restrict__ kbuf,
    const u16* __restrict__ vtb, float* __restrict__ out)
{
    __shared__ __align__(16) short plds[8][2][16 * 72];  // P^T per wave per q (36.9 KiB)
    __shared__ __align__(16) float ldso[8][16][68];      // O^T partials (34.8 KiB)
    __shared__ float ldsm[8][16];                        // m partials [w][t]
    __shared__ float ldsl[8][16];                        // l partials [w][t]

    int tid = threadIdx.x;
    int lane = tid & 63, w = tid >> 6;   // 8 waves
    int m = lane & 15, quad = lane >> 4;

    int idx = blockIdx.x;
    int xcd = idx & 7;                    // HW round-robins blockIdx across XCDs
    int batch = xcd >> 1;                 // 2 XCDs per batch
    int pair = (idx >> 3) * 2 + (xcd & 1);  // 0..63

    const u16* kp = kbuf + (size_t)(batch * SEQ + m) * HD + quad * 8;  // + s*HD
    const u16* vp = vtb + (size_t)(batch * HD + m) * SEQ + quad * 8;   // + nt*16*SEQ + s

    bf16x8 ones;
#pragma unroll
    for (int i = 0; i < 8; i++) ones[i] = (short)0x3F80;   // bf16 1.0

    for (int half = 0; half < 2; half++) {
        int jj = half ? pair : (127 - pair);   // heavy tile first
        int t0 = jj * 32;
        int nkb = (jj >> 1) + 1;               // 64-key blocks needed
        int lastkb = nkb - 1;

        const u16* qpb = qb + (size_t)(batch * SEQ + t0 + m) * HD + quad * 8;
        bf16x8 q0[2], q1[2];
#pragma unroll
        for (int q = 0; q < 2; q++) {
            q0[q] = *(const bf16x8*)(qpb + (size_t)(q * 16) * HD);
            q1[q] = *(const bf16x8*)(qpb + (size_t)(q * 16) * HD + 32);
        }

        float mst[2];
        f32x4 o[2][4], ol[2];
#pragma unroll
        for (int q = 0; q < 2; q++) {
            mst[q] = -1e30f;
            ol[q] = (f32x4){0.f, 0.f, 0.f, 0.f};
#pragma unroll
            for (int nt = 0; nt < 4; nt++) o[q][nt] = (f32x4){0.f, 0.f, 0.f, 0.f};
        }

        int cnt = (nkb > w) ? ((nkb - w + 7) >> 3) : 0;
        int kb = w;

        // preload K A-frags for first kb (in-bounds even when cnt==0: kb<=7)
        bf16x8 k0[4], k1[4];
#pragma unroll
        for (int st = 0; st < 4; st++) {
            k0[st] = *(const bf16x8*)(kp + (size_t)(kb * 64 + st * 16) * HD);
            k1[st] = *(const bf16x8*)(kp + (size_t)(kb * 64 + st * 16) * HD + 32);
        }

        for (int it = 0; it < cnt; it++, kb += 8) {
            int s0 = kb * 64;
            bool diag = (kb == lastkb);

            // V loads issue early; consumed after softmax (~latency hidden)
            bf16x8 vf0[4], vf1[4];
#pragma unroll
            for (int nt = 0; nt < 4; nt++) {
                vf0[nt] = *(const bf16x8*)(vp + (size_t)(nt * 16) * SEQ + s0);
                vf1[nt] = *(const bf16x8*)(vp + (size_t)(nt * 16) * SEQ + s0 + 32);
            }

            // S^T = K Q^T for both q sub-tiles (scores pre-scaled via Q)
            f32x4 s[2][4];
#pragma unroll
            for (int q = 0; q < 2; q++)
#pragma unroll
                for (int st = 0; st < 4; st++) {
                    f32x4 a = (f32x4){0.f, 0.f, 0.f, 0.f};
                    a = __builtin_amdgcn_mfma_f32_16x16x32_bf16(k0[st], q0[q], a, 0, 0, 0);
                    a = __builtin_amdgcn_mfma_f32_16x16x32_bf16(k1[st], q1[q], a, 0, 0, 0);
                    s[q][st] = a;
                }

            // last K use done: prefetch next key-block for this wave
            if (it + 1 < cnt) {
                int sn = s0 + 512;
#pragma unroll
                for (int st = 0; st < 4; st++) {
                    k0[st] = *(const bf16x8*)(kp + (size_t)(sn + st * 16) * HD);
                    k1[st] = *(const bf16x8*)(kp + (size_t)(sn + st * 16) * HD + 32);
                }
            }

            // causal mask only on the diagonal block (wave-uniform branch)
            if (diag) {
#pragma unroll
                for (int q = 0; q < 2; q++)
#pragma unroll
                    for (int st = 0; st < 4; st++)
#pragma unroll
                        for (int r = 0; r < 4; r++) {
                            int key = s0 + st * 16 + quad * 4 + r;
                            if (key > t0 + q * 16 + m) s[q][st][r] = -1e30f;
                        }
            }

            // softmax for both q-chains (independent -> ILP), pack P^T to LDS
#pragma unroll
            for (int q = 0; q < 2; q++) {
                float mx = -1e30f;
#pragma unroll
                for (int st = 0; st < 4; st++) {
                    float a01 = fmaxf(s[q][st][0], s[q][st][1]);
                    float a23 = fmaxf(s[q][st][2], s[q][st][3]);
                    mx = fmaxf(mx, fmaxf(a01, a23));
                }
                mx = fmaxf(mx, __shfl_xor(mx, 16, 64));
                mx = fmaxf(mx, __shfl_xor(mx, 32, 64));

                // defer-max: only rescale when max grew past threshold
                if (__any(mx > mst[q] + 8.0f)) {
                    float mn = fmaxf(mst[q], mx);
                    float al = exp2f(mst[q] - mn);
#pragma unroll
                    for (int nt = 0; nt < 4; nt++)
#pragma unroll
                        for (int r = 0; r < 4; r++) o[q][nt][r] *= al;
                    ol[q][0] *= al;   // only reg 0 of ol is ever read
                    mst[q] = mn;
                }

                short* pwq = &plds[w][q][0];
#pragma unroll
                for (int st = 0; st < 4; st++) {
                    float e0 = exp2f(s[q][st][0] - mst[q]);
                    float e1 = exp2f(s[q][st][1] - mst[q]);
                    float e2 = exp2f(s[q][st][2] - mst[q]);
                    float e3 = exp2f(s[q][st][3] - mst[q]);
                    uint2 pk2;
                    pk2.x = cvtpk_bf16(e0, e1);
                    pk2.y = cvtpk_bf16(e2, e3);
                    *(uint2*)(pwq + m * 72 + st * 16 + quad * 4) = pk2;
                }
            }
            __asm__ volatile("" ::: "memory");   // pack-writes before frag-reads

#pragma unroll
            for (int q = 0; q < 2; q++) {
                const short* pwq = &plds[w][q][0];
                bf16x8 p0 = *(const bf16x8*)(pwq + m * 72 + quad * 8);
                bf16x8 p1 = *(const bf16x8*)(pwq + m * 72 + 32 + quad * 8);

                // O^T += V^T P^T ; l += ones . P^T (replaces VALU sum-reduce)
#pragma unroll
                for (int nt = 0; nt < 4; nt++) {
                    o[q][nt] = __builtin_amdgcn_mfma_f32_16x16x32_bf16(vf0[nt], p0, o[q][nt], 0, 0, 0);
                    o[q][nt] = __builtin_amdgcn_mfma_f32_16x16x32_bf16(vf1[nt], p1, o[q][nt], 0, 0, 0);
                }
                ol[q] = __builtin_amdgcn_mfma_f32_16x16x32_bf16(ones, p0, ol[q], 0, 0, 0);
                ol[q] = __builtin_amdgcn_mfma_f32_16x16x32_bf16(ones, p1, ol[q], 0, 0, 0);
            }
        }

        // merge 8 wave-partials per q sub-tile (waves with cnt==0 publish
        // m=-1e30, l=0, O=0 -> zero weight; wave 0 always has work)
#pragma unroll
        for (int q = 0; q < 2; q++) {
            if (quad == 0) { ldsm[w][m] = mst[q]; ldsl[w][m] = ol[q][0]; }
#pragma unroll
            for (int nt = 0; nt < 4; nt++)
                *(f32x4*)&ldso[w][m][nt * 16 + quad * 4] = o[q][nt];
            __syncthreads();

            if (tid < 256) {
                int t = tid >> 4, vg = tid & 15;
                float mmax = -1e30f;
#pragma unroll
                for (int u = 0; u < 8; u++) mmax = fmaxf(mmax, ldsm[u][t]);
                float L = 0.f;
                f32x4 acc = (f32x4){0.f, 0.f, 0.f, 0.f};
#pragma unroll
                for (int u = 0; u < 8; u++) {
                    float c = exp2f(ldsm[u][t] - mmax);
                    L += ldsl[u][t] * c;
                    f32x4 ov = *(const f32x4*)&ldso[u][t][vg * 4];
#pragma unroll
                    for (int i2 = 0; i2 < 4; i2++) acc[i2] += ov[i2] * c;
                }
                float inv = 1.0f / L;
                f32x4 res;
#pragma unroll
                for (int i2 = 0; i2 < 4; i2++) res[i2] = acc[i2] * inv;
                *(f32x4*)(out + (size_t)(batch * SEQ + t0 + q * 16 + t) * OC + CIN + vg * 4) = res;
            }
            __syncthreads();   // ldso reused by next q / next tile
        }
    }
}

// ---------------------------------------------------------------------------
extern "C" void kernel_launch(void* const* d_in, const int* in_sizes, int n_in,
                              void* d_out, int out_size, void* d_ws, size_t ws_size,
                              hipStream_t stream) {
    const float* x  = (const float*)d_in[0];
    const float* Wq = (const float*)d_in[1];
    const float* bq = (const float*)d_in[2];
    const float* Wk = (const float*)d_in[3];
    const float* bk = (const float*)d_in[4];
    const float* Wv = (const float*)d_in[5];
    const float* bv = (const float*)d_in[6];
    float* out = (float*)d_out;

    u16* ws  = (u16*)d_ws;
    u16* wt  = ws;                          // 192*512 elems (pad to 128K)
    u16* qb  = ws + 131072;                 // 16384*64 = 1M elems
    u16* kb  = qb + 16384 * 64;
    u16* vtb = kb + 16384 * 64;             // transposed v: [4][64][4096]

    prep_wt<<<dim3(192), dim3(256), 0, stream>>>(Wq, Wk, Wv, wt);
    proj<<<dim3(256), dim3(256), 0, stream>>>(x, wt, bq, bk, bv, qb, kb, vtb, out);
    attn<<<dim3(256), dim3(512), 0, stream>>>(qb, kb, vtb, out);
}